// Round 1
// baseline (700.325 us; speedup 1.0000x reference)
//
#include <hip/hip_runtime.h>

#define BN 8
#define NN 512
#define FIN 128
#define FOUT 64
#define ALPHA 0.2f

// Kernel 1: Wh[b,n,o] = sum_i h[b,n,i] * W[i,o]; e_i[bn] = Wh·a_i; e_j[bn] = Wh·a_j
__global__ __launch_bounds__(64) void wh_kernel(
    const float* __restrict__ h, const float* __restrict__ W,
    const float* __restrict__ a,
    float* __restrict__ Wh, float* __restrict__ e_i, float* __restrict__ e_j) {
    int bn = blockIdx.x;          // 0..4095
    int o  = threadIdx.x;         // 0..63
    __shared__ float hrow[FIN];
    hrow[o]      = h[bn * FIN + o];
    hrow[o + 64] = h[bn * FIN + 64 + o];
    __syncthreads();
    float acc = 0.f;
#pragma unroll 8
    for (int i = 0; i < FIN; ++i)
        acc = fmaf(hrow[i], W[i * FOUT + o], acc);   // W reads coalesced, L1-resident
    Wh[bn * FOUT + o] = acc;
    float pi = acc * a[o];
    float pj = acc * a[FOUT + o];
#pragma unroll
    for (int off = 32; off >= 1; off >>= 1) {
        pi += __shfl_xor(pi, off, 64);
        pj += __shfl_xor(pj, off, 64);
    }
    if (o == 0) { e_i[bn] = pi; e_j[bn] = pj; }
}

// Kernel 2: per (b,i): s_j = leaky(e_i + e_j[j] + a_e * (edge[b,i,j,:]·U)),
// softmax over j, out[b,i,:] = sum_j p_j * Wh[b,j,:]
__global__ __launch_bounds__(256) void attn_kernel(
    const float* __restrict__ edge, const float* __restrict__ U,
    const float* __restrict__ a, const float* __restrict__ Wh,
    const float* __restrict__ e_i, const float* __restrict__ e_j,
    float* __restrict__ out) {
    int bi   = blockIdx.x;        // b*NN + i
    int b    = bi >> 9;
    int tid  = threadIdx.x;
    int lane = tid & 63;
    int wave = tid >> 6;

    __shared__ float s_lds[NN];
    __shared__ float ej_lds[NN];
    __shared__ float red[8];
    __shared__ float accbuf[4][FOUT];

    // preload e_j row for this b (coalesced)
    ej_lds[tid]       = e_j[(b << 9) + tid];
    ej_lds[tid + 256] = e_j[(b << 9) + tid + 256];

    float a_e = a[2 * FOUT];
    float eiv = e_i[bi];
    int   sub = lane & 15;                      // which float4 of the 64-wide o row
    float4 Uv = ((const float4*)U)[sub];
    const float4* erow = (const float4*)(edge + (size_t)bi * (NN * FOUT));
    int jbase = (wave << 2) + (lane >> 4);      // each wave covers 4 consecutive j
    __syncthreads();

    // Stage 1: edge scores. Block streams 4 KiB contiguous per iteration.
#pragma unroll 4
    for (int it = 0; it < 32; ++it) {
        int j = (it << 4) + jbase;
        float4 ef = erow[(j << 4) + sub];
        float p = ef.x * Uv.x + ef.y * Uv.y + ef.z * Uv.z + ef.w * Uv.w;
        p += __shfl_xor(p, 8, 16);
        p += __shfl_xor(p, 4, 16);
        p += __shfl_xor(p, 2, 16);
        p += __shfl_xor(p, 1, 16);
        if (sub == 0) {
            float s = eiv + ej_lds[j] + a_e * p;
            s_lds[j] = (s >= 0.f) ? s : (ALPHA * s);
        }
    }
    __syncthreads();

    // Stage 2: softmax over 512 values
    float m = fmaxf(s_lds[tid], s_lds[tid + 256]);
#pragma unroll
    for (int off = 32; off >= 1; off >>= 1) m = fmaxf(m, __shfl_xor(m, off, 64));
    if (lane == 0) red[wave] = m;
    __syncthreads();
    m = fmaxf(fmaxf(red[0], red[1]), fmaxf(red[2], red[3]));
    float v0 = expf(s_lds[tid] - m);
    float v1 = expf(s_lds[tid + 256] - m);
    float ssum = v0 + v1;
    s_lds[tid] = v0;                 // each location touched by exactly one thread
    s_lds[tid + 256] = v1;
#pragma unroll
    for (int off = 32; off >= 1; off >>= 1) ssum += __shfl_xor(ssum, off, 64);
    if (lane == 0) red[4 + wave] = ssum;
    __syncthreads();
    float inv = 1.0f / (red[4] + red[5] + red[6] + red[7]);

    // Stage 3: out[o] = inv * sum_j p_j * Wh[b,j,o]   (Wh L2-resident)
    int o = tid & 63, chunk = tid >> 6;
    const float* WhB = Wh + (((size_t)b) << 9) * FOUT;
    float acc = 0.f;
    int j0 = chunk << 7;
#pragma unroll 8
    for (int j = j0; j < j0 + 128; ++j)
        acc = fmaf(s_lds[j], WhB[(j << 6) + o], acc);   // lanes=o coalesced, s_lds broadcast
    accbuf[chunk][o] = acc;
    __syncthreads();
    if (chunk == 0) {
        float r = (accbuf[0][o] + accbuf[1][o] + accbuf[2][o] + accbuf[3][o]) * inv;
        out[((size_t)bi << 6) + o] = r;
    }
}

extern "C" void kernel_launch(void* const* d_in, const int* in_sizes, int n_in,
                              void* d_out, int out_size, void* d_ws, size_t ws_size,
                              hipStream_t stream) {
    const float* h    = (const float*)d_in[0];   // (8,512,128)
    const float* edge = (const float*)d_in[1];   // (8,512,512,64)
    const float* W    = (const float*)d_in[2];   // (1,128,64)
    const float* U    = (const float*)d_in[3];   // (1,64)
    const float* a    = (const float*)d_in[4];   // (1,129)
    float* out = (float*)d_out;                  // (8,512,64)

    float* Wh  = (float*)d_ws;                   // 262144 floats
    float* e_i = Wh + BN * NN * FOUT;            // 4096
    float* e_j = e_i + BN * NN;                  // 4096

    wh_kernel<<<BN * NN, 64, 0, stream>>>(h, W, a, Wh, e_i, e_j);
    attn_kernel<<<BN * NN, 256, 0, stream>>>(edge, U, a, Wh, e_i, e_j, out);
}